// Round 7
// baseline (228.353 us; speedup 1.0000x reference)
//
#include <hip/hip_runtime.h>

#define N_NODES 50000
#define N_EDGES 640000
#define NSCANB  196   // ceil(50000/256)
#define MAXD    64    // bin capacity; deg ~ Poisson(12.8), P(max>=48) ~ 3e-14
#define NBUCK   196   // coarse buckets (dst>>8), 256 nodes each
#define BUCKCAP 4096  // per-bucket capacity; mean 3277, sigma 57 -> +14 sigma
#define EPB     2048  // edges per k_part block
#define NPARTB  313   // ceil(640000/2048)

// workspace layout (4B units)
#define OFF_HTMPB    0          // ushort[50000][128] bf16 h*dinv (pre-scaled)
#define OFF_OBF      3200000    // ushort[50000][128] bf16 out
#define OFF_DEG      6400000    // int[50000]
#define OFF_DINV     6450000    // float[50000] rsqrt(deg+1)
#define OFF_E        6500000    // float[50000]
#define OFF_PMIN     6550000    // float[256]
#define OFF_PS0      6550256    // float[256]
#define OFF_PS1      6550512    // float[256]
#define OFF_WT       6550768    // ushort[16384] bf16 W^T = 8192 floats
#define OFF_GCUR     6558960    // int[256] coarse-bucket cursors
#define OFF_PART     6559216    // uint[196*4096] partitioned edges
#define OFF_EBIN     7362032    // ushort[50000*64] node bins (src ids)

typedef __attribute__((ext_vector_type(8))) short bf16x8;
typedef __attribute__((ext_vector_type(4))) float f32x4;
typedef __attribute__((ext_vector_type(4))) unsigned uv4;

__device__ __forceinline__ unsigned short f2bf(float f) {  // RNE
    unsigned u = __float_as_uint(f);
    unsigned r = u + 0x7fffu + ((u >> 16) & 1u);
    return (unsigned short)(r >> 16);
}
__device__ __forceinline__ float bflo(unsigned u) { return __uint_as_float(u << 16); }
__device__ __forceinline__ float bfhi(unsigned u) { return __uint_as_float(u & 0xffff0000u); }
// non-temporal 16B row-fragment load: bypass L1 allocation (rows are read-once per wave)
__device__ __forceinline__ uv4 ntload(const unsigned short* p) {
    return __builtin_nontemporal_load((const uv4*)p);
}

// init: zero bucket cursors + build bf16 W^T in global ws (32 KB, one-off)
__global__ __launch_bounds__(256) void k_init(const float* __restrict__ W,
                                              int* __restrict__ gcursor,
                                              unsigned short* __restrict__ wtg) {
    int gtid = blockIdx.x * 256 + threadIdx.x;
    if (gtid < NBUCK) gcursor[gtid] = 0;
    if (gtid < 4096) {
        int k = gtid >> 5, n4 = (gtid & 31) * 4;
        float4 v = *(const float4*)(W + k * 128 + n4);
        wtg[(n4 + 0) * 128 + k] = f2bf(v.x);
        wtg[(n4 + 1) * 128 + k] = f2bf(v.y);
        wtg[(n4 + 2) * 128 + k] = f2bf(v.z);
        wtg[(n4 + 3) * 128 + k] = f2bf(v.w);
    }
}

// Pass 1: partition edges into 196 coarse dst-range buckets.
__global__ __launch_bounds__(256) void k_part(const int* __restrict__ src,
                                              const int* __restrict__ dst,
                                              int* __restrict__ gcursor,
                                              unsigned* __restrict__ part) {
    __shared__ int hist[NBUCK];
    __shared__ int base[NBUCK];
    int tid = threadIdx.x;
    if (tid < NBUCK) hist[tid] = 0;
    __syncthreads();
    int e0 = blockIdx.x * EPB;
    unsigned val[8]; int bk[8]; int rk[8];
    #pragma unroll
    for (int j = 0; j < 8; j++) {
        int e = e0 + j * 256 + tid;
        if (e < N_EDGES) {
            int s = src[e], d = dst[e];
            int bc = d >> 8;
            if ((unsigned)bc >= NBUCK) bc = NBUCK - 1;   // defensive clamp
            bk[j] = bc;
            val[j] = ((unsigned)(d & 255) << 16) | ((unsigned)s & 0xffffu);
            rk[j] = atomicAdd(&hist[bc], 1);
        } else { bk[j] = -1; val[j] = 0u; rk[j] = 0; }
    }
    __syncthreads();
    if (tid < NBUCK) base[tid] = atomicAdd(&gcursor[tid], hist[tid]);
    __syncthreads();
    #pragma unroll
    for (int j = 0; j < 8; j++) {
        if (bk[j] >= 0) {
            int p = base[bk[j]] + rk[j];
            if ((unsigned)p < BUCKCAP) part[bk[j] * BUCKCAP + p] = val[j];
        }
    }
}

// Pass 2: per-bucket LDS binning, coalesced writeout; emits deg + dinv.
__global__ __launch_bounds__(256) void k_bin(const int* __restrict__ gcursor,
                                             const unsigned* __restrict__ part,
                                             unsigned short* __restrict__ ebin,
                                             int* __restrict__ deg,
                                             float* __restrict__ dinv) {
    __shared__ __align__(16) unsigned short bins[256][MAXD];
    __shared__ int cnt[256];
    int tid = threadIdx.x, bkt = blockIdx.x;
    cnt[tid] = 0;
    __syncthreads();
    int M = gcursor[bkt];
    if (M > BUCKCAP) M = BUCKCAP;
    if (M < 0) M = 0;
    for (int i = tid; i < M; i += 256) {
        unsigned v = part[bkt * BUCKCAP + i];
        int ln = (v >> 16) & 255;
        int pos = atomicAdd(&cnt[ln], 1);
        if (pos < MAXD) bins[ln][pos] = (unsigned short)(v & 0xffffu);
    }
    __syncthreads();
    int node = bkt * 256 + tid;
    if (node < N_NODES) {
        int dg = cnt[tid]; if (dg > MAXD) dg = MAXD;
        deg[node] = dg;
        dinv[node] = rsqrtf((float)(dg + 1));
    }
    int nvalid = N_NODES - bkt * 256; if (nvalid > 256) nvalid = 256;
    if (nvalid < 0) nvalid = 0;
    int lim = nvalid * MAXD / 8;  // uint4 count
    const uint4* bs = (const uint4*)&bins[0][0];
    uint4* gb = (uint4*)(ebin + (size_t)bkt * 256 * MAXD);
    for (int i = tid; i < lim; i += 256) gb[i] = bs[i];
}

// Pure bf16 MFMA GEMM with LDS-staged x tile (32 rows x 128, pad stride 132).
// Stores bf16(h * dinv_row), node-major [50000][128].
__global__ __launch_bounds__(256) void k_gemm(const float* __restrict__ x,
                                              const unsigned short* __restrict__ wtg,
                                              const float* __restrict__ dinv,
                                              unsigned short* __restrict__ htmpb) {
    __shared__ __align__(16) float xs[32][132];   // 132-float stride: 16B-aligned rows
    int tid = threadIdx.x;
    // cooperative stage: 8 threads/row, 4 float4 each
    {
        int r = tid >> 3;
        int grow0 = blockIdx.x * 32 + r;
        int rowg = grow0 < N_NODES ? grow0 : N_NODES - 1;
        #pragma unroll
        for (int c = 0; c < 4; c++) {
            int col4 = (tid & 7) + c * 8;
            float4 v = *(const float4*)(x + rowg * 128 + col4 * 4);
            *(float4*)&xs[r][col4 * 4] = v;
        }
    }
    __syncthreads();
    int wave = tid >> 6, lane = tid & 63, quad = lane >> 4, m16 = lane & 15;
    int r0 = blockIdx.x * 32 + (wave & 1) * 16;
    int lr = (wave & 1) * 16 + m16;         // local LDS row
    int ch = (wave >> 1) * 4;               // col-tile base (4 tiles of 16)
    f32x4 acc[4];
    #pragma unroll
    for (int c = 0; c < 4; c++) acc[c] = (f32x4){0.f, 0.f, 0.f, 0.f};
    #pragma unroll
    for (int kt = 0; kt < 4; kt++) {
        int koff = kt * 32 + quad * 8;
        float4 xa = *(const float4*)&xs[lr][koff];
        float4 xb = *(const float4*)&xs[lr][koff + 4];
        bf16x8 af;
        af[0] = (short)f2bf(xa.x); af[1] = (short)f2bf(xa.y);
        af[2] = (short)f2bf(xa.z); af[3] = (short)f2bf(xa.w);
        af[4] = (short)f2bf(xb.x); af[5] = (short)f2bf(xb.y);
        af[6] = (short)f2bf(xb.z); af[7] = (short)f2bf(xb.w);
        #pragma unroll
        for (int c = 0; c < 4; c++) {
            bf16x8 bfrag = *(const bf16x8*)(wtg + ((ch + c) * 16 + m16) * 128 + koff);
            acc[c] = __builtin_amdgcn_mfma_f32_16x16x32_bf16(af, bfrag, acc[c], 0, 0, 0);
        }
    }
    #pragma unroll
    for (int reg = 0; reg < 4; reg++) {
        int grow = r0 + quad * 4 + reg;
        if (grow < N_NODES) {
            float dv = dinv[grow];
            #pragma unroll
            for (int c = 0; c < 4; c++)
                htmpb[grow * 128 + (ch + c) * 16 + m16] = f2bf(acc[c][reg] * dv);
        }
    }
}

// Gather, 16 lanes/node, non-temporal uint4 row loads (bypass L1 alloc).
__global__ __launch_bounds__(256) void k_gather(const unsigned short* __restrict__ htmpb,
                                                const int* __restrict__ deg,
                                                const float* __restrict__ dinv,
                                                const float* __restrict__ b,
                                                const unsigned short* __restrict__ ebin,
                                                float* __restrict__ out,
                                                unsigned short* __restrict__ obf) {
    int node = blockIdx.x * 16 + (threadIdx.x >> 4);
    int lane = threadIdx.x & 15;
    int c8 = lane * 8;                       // 8 bf16 cols per lane
    int dg = deg[node]; if (dg > MAXD) dg = MAXD; if (dg < 0) dg = 0;
    float di = dinv[node];
    float4 bv0 = *(const float4*)(b + c8);
    float4 bv1 = *(const float4*)(b + c8 + 4);
    uv4 hv = ntload(htmpb + node * 128 + c8);
    float a0 = bflo(hv[0]), a1 = bfhi(hv[0]), a2 = bflo(hv[1]), a3 = bfhi(hv[1]);
    float a4 = bflo(hv[2]), a5 = bfhi(hv[2]), a6 = bflo(hv[3]), a7 = bfhi(hv[3]);
    float c0 = 0.f, c1 = 0.f, c2c = 0.f, c3 = 0.f, c4 = 0.f, c5 = 0.f, c6 = 0.f, c7 = 0.f;
    const unsigned short* bin = ebin + node * MAXD;
    int k = 0;
    for (; k + 3 < dg; k += 4) {
        uint2 bw = *(const uint2*)(bin + k);
        int s0 = bw.x & 0xffff, s1 = bw.x >> 16;
        int s2 = bw.y & 0xffff, s3 = bw.y >> 16;
        uv4 u0 = ntload(htmpb + s0 * 128 + c8);
        uv4 u1 = ntload(htmpb + s1 * 128 + c8);
        uv4 u2 = ntload(htmpb + s2 * 128 + c8);
        uv4 u3 = ntload(htmpb + s3 * 128 + c8);
        a0 += bflo(u0[0]); a1 += bfhi(u0[0]); a2 += bflo(u0[1]); a3 += bfhi(u0[1]);
        a4 += bflo(u0[2]); a5 += bfhi(u0[2]); a6 += bflo(u0[3]); a7 += bfhi(u0[3]);
        c0 += bflo(u1[0]); c1 += bfhi(u1[0]); c2c += bflo(u1[1]); c3 += bfhi(u1[1]);
        c4 += bflo(u1[2]); c5 += bfhi(u1[2]); c6 += bflo(u1[3]); c7 += bfhi(u1[3]);
        a0 += bflo(u2[0]); a1 += bfhi(u2[0]); a2 += bflo(u2[1]); a3 += bfhi(u2[1]);
        a4 += bflo(u2[2]); a5 += bfhi(u2[2]); a6 += bflo(u2[3]); a7 += bfhi(u2[3]);
        c0 += bflo(u3[0]); c1 += bfhi(u3[0]); c2c += bflo(u3[1]); c3 += bfhi(u3[1]);
        c4 += bflo(u3[2]); c5 += bfhi(u3[2]); c6 += bflo(u3[3]); c7 += bfhi(u3[3]);
    }
    for (; k < dg; k++) {
        int s0 = bin[k];
        uv4 u0 = ntload(htmpb + s0 * 128 + c8);
        a0 += bflo(u0[0]); a1 += bfhi(u0[0]); a2 += bflo(u0[1]); a3 += bfhi(u0[1]);
        a4 += bflo(u0[2]); a5 += bfhi(u0[2]); a6 += bflo(u0[3]); a7 += bfhi(u0[3]);
    }
    a0 += c0; a1 += c1; a2 += c2c; a3 += c3; a4 += c4; a5 += c5; a6 += c6; a7 += c7;
    a0 = bv0.x + di * a0; a1 = bv0.y + di * a1; a2 = bv0.z + di * a2; a3 = bv0.w + di * a3;
    a4 = bv1.x + di * a4; a5 = bv1.y + di * a5; a6 = bv1.z + di * a6; a7 = bv1.w + di * a7;
    *(float4*)(out + node * 128 + c8)     = make_float4(a0, a1, a2, a3);
    *(float4*)(out + node * 128 + c8 + 4) = make_float4(a4, a5, a6, a7);
    uint4 pk;
    pk.x = (unsigned)f2bf(a0) | ((unsigned)f2bf(a1) << 16);
    pk.y = (unsigned)f2bf(a2) | ((unsigned)f2bf(a3) << 16);
    pk.z = (unsigned)f2bf(a4) | ((unsigned)f2bf(a5) << 16);
    pk.w = (unsigned)f2bf(a6) | ((unsigned)f2bf(a7) << 16);
    *(uint4*)(obf + node * 128 + c8) = pk;
}

// Energy, 16 lanes/node, non-temporal uint4: E[d] = sum_s ||o_s - o_d||^2.
__global__ __launch_bounds__(256) void k_energy(const unsigned short* __restrict__ obf,
                                                const int* __restrict__ deg,
                                                const unsigned short* __restrict__ ebin,
                                                float* __restrict__ E) {
    int node = blockIdx.x * 16 + (threadIdx.x >> 4);
    int lane = threadIdx.x & 15;
    int c8 = lane * 8;
    int dg = deg[node]; if (dg > MAXD) dg = MAXD; if (dg < 0) dg = 0;
    uv4 ud = ntload(obf + node * 128 + c8);
    float o0 = bflo(ud[0]), o1 = bfhi(ud[0]), o2 = bflo(ud[1]), o3 = bfhi(ud[1]);
    float o4 = bflo(ud[2]), o5 = bfhi(ud[2]), o6 = bflo(ud[3]), o7 = bfhi(ud[3]);
    float acc = 0.f, acc2 = 0.f;
    const unsigned short* bin = ebin + node * MAXD;
    int k = 0;
    for (; k + 3 < dg; k += 4) {
        uint2 bw = *(const uint2*)(bin + k);
        int s0 = bw.x & 0xffff, s1 = bw.x >> 16;
        int s2 = bw.y & 0xffff, s3 = bw.y >> 16;
        uv4 a = ntload(obf + s0 * 128 + c8);
        uv4 c = ntload(obf + s1 * 128 + c8);
        uv4 g = ntload(obf + s2 * 128 + c8);
        uv4 h = ntload(obf + s3 * 128 + c8);
        float d0, d1, d2, d3, d4, d5, d6, d7;
        d0 = bflo(a[0]) - o0; d1 = bfhi(a[0]) - o1; d2 = bflo(a[1]) - o2; d3 = bfhi(a[1]) - o3;
        d4 = bflo(a[2]) - o4; d5 = bfhi(a[2]) - o5; d6 = bflo(a[3]) - o6; d7 = bfhi(a[3]) - o7;
        acc  += d0*d0 + d1*d1 + d2*d2 + d3*d3 + d4*d4 + d5*d5 + d6*d6 + d7*d7;
        d0 = bflo(c[0]) - o0; d1 = bfhi(c[0]) - o1; d2 = bflo(c[1]) - o2; d3 = bfhi(c[1]) - o3;
        d4 = bflo(c[2]) - o4; d5 = bfhi(c[2]) - o5; d6 = bflo(c[3]) - o6; d7 = bfhi(c[3]) - o7;
        acc2 += d0*d0 + d1*d1 + d2*d2 + d3*d3 + d4*d4 + d5*d5 + d6*d6 + d7*d7;
        d0 = bflo(g[0]) - o0; d1 = bfhi(g[0]) - o1; d2 = bflo(g[1]) - o2; d3 = bfhi(g[1]) - o3;
        d4 = bflo(g[2]) - o4; d5 = bfhi(g[2]) - o5; d6 = bflo(g[3]) - o6; d7 = bfhi(g[3]) - o7;
        acc  += d0*d0 + d1*d1 + d2*d2 + d3*d3 + d4*d4 + d5*d5 + d6*d6 + d7*d7;
        d0 = bflo(h[0]) - o0; d1 = bfhi(h[0]) - o1; d2 = bflo(h[1]) - o2; d3 = bfhi(h[1]) - o3;
        d4 = bflo(h[2]) - o4; d5 = bfhi(h[2]) - o5; d6 = bflo(h[3]) - o6; d7 = bfhi(h[3]) - o7;
        acc2 += d0*d0 + d1*d1 + d2*d2 + d3*d3 + d4*d4 + d5*d5 + d6*d6 + d7*d7;
    }
    for (; k < dg; k++) {
        int s0 = bin[k];
        uv4 a = ntload(obf + s0 * 128 + c8);
        float d0 = bflo(a[0]) - o0, d1 = bfhi(a[0]) - o1, d2 = bflo(a[1]) - o2, d3 = bfhi(a[1]) - o3;
        float d4 = bflo(a[2]) - o4, d5 = bfhi(a[2]) - o5, d6 = bflo(a[3]) - o6, d7 = bfhi(a[3]) - o7;
        acc += d0*d0 + d1*d1 + d2*d2 + d3*d3 + d4*d4 + d5*d5 + d6*d6 + d7*d7;
    }
    acc += acc2;
    #pragma unroll
    for (int off = 8; off; off >>= 1) acc += __shfl_xor(acc, off);  // 16-lane group
    if (lane == 0) E[node] = acc;
}

// 196 blocks: per-block partial min + partial softmax sums (local-min-shifted).
__global__ __launch_bounds__(256) void k_esoft(const float* __restrict__ E,
                                               const float* __restrict__ temp,
                                               float* __restrict__ pmin,
                                               float* __restrict__ ps0,
                                               float* __restrict__ ps1) {
    __shared__ float fred[12];
    int tid = threadIdx.x;
    int i = blockIdx.x * 256 + tid;
    int lane = tid & 63, wid = tid >> 6;
    float e = (i < N_NODES) ? E[i] : 3.402823466e38f;
    float m = e;
    #pragma unroll
    for (int off = 32; off; off >>= 1) m = fminf(m, __shfl_xor(m, off));
    if (lane == 0) fred[wid] = m;
    __syncthreads();
    float bm = fminf(fminf(fred[0], fred[1]), fminf(fred[2], fred[3]));
    float T = temp[0];
    float s0 = 0.f, s1 = 0.f;
    if (i < N_NODES) {
        float dd = (bm - e) / T;
        float ed = __expf(dd);
        s0 = ed; s1 = ed * dd;
    }
    #pragma unroll
    for (int off = 32; off; off >>= 1) { s0 += __shfl_xor(s0, off); s1 += __shfl_xor(s1, off); }
    __syncthreads();
    if (lane == 0) { fred[4 + wid] = s0; fred[8 + wid] = s1; }
    __syncthreads();
    if (tid == 0) {
        pmin[blockIdx.x] = bm;
        ps0[blockIdx.x] = fred[4] + fred[5] + fred[6] + fred[7];
        ps1[blockIdx.x] = fred[8] + fred[9] + fred[10] + fred[11];
    }
}

// Gradient: merge 196 partials (redundant per block), then sparse scatter.
__global__ __launch_bounds__(256) void k_grad(const int* __restrict__ deg,
                                              const unsigned short* __restrict__ ebin,
                                              const float* __restrict__ E,
                                              const float* __restrict__ temp,
                                              const float* __restrict__ pmin,
                                              const float* __restrict__ ps0,
                                              const float* __restrict__ ps1,
                                              const float* __restrict__ weight,
                                              float* __restrict__ out) {
    __shared__ float fred[12];
    int tid = threadIdx.x;
    int lane = tid & 63, wid = tid >> 6;

    float pm = (tid < NSCANB) ? pmin[tid] : 3.402823466e38f;
    float m = pm;
    #pragma unroll
    for (int off = 32; off; off >>= 1) m = fminf(m, __shfl_xor(m, off));
    if (lane == 0) fred[wid] = m;
    __syncthreads();
    float gmin = fminf(fminf(fred[0], fred[1]), fminf(fred[2], fred[3]));
    float T = temp[0];
    float s0 = 0.f, s1 = 0.f;
    if (tid < NSCANB) {
        float dl = (gmin - pm) / T;        // <= 0
        float ex = __expf(dl);
        float b0 = ps0[tid], b1 = ps1[tid];
        s0 = ex * b0;
        s1 = ex * (b1 + dl * b0);
    }
    #pragma unroll
    for (int off = 32; off; off >>= 1) { s0 += __shfl_xor(s0, off); s1 += __shfl_xor(s1, off); }
    __syncthreads();
    if (lane == 0) { fred[4 + wid] = s0; fred[8 + wid] = s1; }
    __syncthreads();
    float S0 = fred[4] + fred[5] + fred[6] + fred[7];
    float S1 = fred[8] + fred[9] + fred[10] + fred[11];

    float wscale = 2.f * weight[0];
    int lane32 = tid & 31;
    int node = blockIdx.x * 8 + (tid >> 5);
    if (node >= N_NODES) return;
    float dd = (gmin - E[node]) / T;
    float qd = (__expf(dd) / S0) * (dd - S1 / S0) / T;
    if (qd == 0.f) return;
    float cc = wscale * qd;
    int dg = deg[node]; if (dg > MAXD) dg = MAXD; if (dg < 0) dg = 0;
    float4 od = *(const float4*)(out + node * 128 + lane32 * 4);
    float sx = 0.f, sy = 0.f, sz = 0.f, sw = 0.f;
    const unsigned short* bin = ebin + node * MAXD;
    for (int k = 0; k < dg; k++) {
        int s = bin[k];
        if (s >= N_NODES) s = N_NODES - 1;   // keeps scatter inside d_out
        float4 a = *(const float4*)(out + s * 128 + lane32 * 4);
        float vx = cc * (a.x - od.x), vy = cc * (a.y - od.y);
        float vz = cc * (a.z - od.z), vw = cc * (a.w - od.w);
        float* os = out + s * 128 + lane32 * 4;
        atomicAdd(os + 0, vx); atomicAdd(os + 1, vy);
        atomicAdd(os + 2, vz); atomicAdd(os + 3, vw);
        sx += vx; sy += vy; sz += vz; sw += vw;
    }
    float* odp = out + node * 128 + lane32 * 4;
    atomicAdd(odp + 0, -sx); atomicAdd(odp + 1, -sy);
    atomicAdd(odp + 2, -sz); atomicAdd(odp + 3, -sw);
}

extern "C" void kernel_launch(void* const* d_in, const int* in_sizes, int n_in,
                              void* d_out, int out_size, void* d_ws, size_t ws_size,
                              hipStream_t stream) {
    const float* x      = (const float*)d_in[0];
    const int*   ei     = (const int*)d_in[1];
    const float* weight = (const float*)d_in[2];
    const float* temp   = (const float*)d_in[3];
    const float* W      = (const float*)d_in[4];
    const float* b      = (const float*)d_in[5];
    float* out = (float*)d_out;
    float* ws  = (float*)d_ws;

    const int* src = ei;
    const int* dst = ei + N_EDGES;

    unsigned short* htmpb = (unsigned short*)(ws + OFF_HTMPB);
    unsigned short* obf   = (unsigned short*)(ws + OFF_OBF);
    int*   deg      = (int*)(ws + OFF_DEG);
    float* dinv     = ws + OFF_DINV;
    float* Earr     = ws + OFF_E;
    float* pminA    = ws + OFF_PMIN;
    float* ps0A     = ws + OFF_PS0;
    float* ps1A     = ws + OFF_PS1;
    unsigned short* wtg = (unsigned short*)(ws + OFF_WT);
    int*   gcursor  = (int*)(ws + OFF_GCUR);
    unsigned* part  = (unsigned*)(ws + OFF_PART);
    unsigned short* ebin = (unsigned short*)(ws + OFF_EBIN);

    k_init<<<16, 256, 0, stream>>>(W, gcursor, wtg);
    k_part<<<NPARTB, 256, 0, stream>>>(src, dst, gcursor, part);
    k_bin<<<NBUCK, 256, 0, stream>>>(gcursor, part, ebin, deg, dinv);
    k_gemm<<<1563, 256, 0, stream>>>(x, wtg, dinv, htmpb);
    k_gather<<<3125, 256, 0, stream>>>(htmpb, deg, dinv, b, ebin, out, obf);
    k_energy<<<3125, 256, 0, stream>>>(obf, deg, ebin, Earr);
    k_esoft<<<NSCANB, 256, 0, stream>>>(Earr, temp, pminA, ps0A, ps1A);
    k_grad<<<6250, 256, 0, stream>>>(deg, ebin, Earr, temp, pminA, ps0A, ps1A, weight, out);
}

// Round 8
// 215.316 us; speedup vs baseline: 1.0605x; 1.0605x over previous
//
#include <hip/hip_runtime.h>

#define N_NODES 50000
#define N_EDGES 640000
#define NSCANB  196   // ceil(50000/256)
#define MAXD    64    // bin capacity; deg ~ Poisson(12.8), P(max>=48) ~ 3e-14
#define NBUCK   196   // coarse buckets (dst>>8), 256 nodes each
#define BUCKCAP 4096  // per-bucket capacity; mean 3277, sigma 57 -> +14 sigma
#define EPB     2048  // edges per k_part block
#define NPARTB  313   // ceil(640000/2048)

// workspace layout (4B units)
#define OFF_HTMPB    0          // ushort[50000][128] bf16 h*dinv (pre-scaled)
#define OFF_OBF      3200000    // ushort[50000][128] bf16 out
#define OFF_DEG      6400000    // int[50000]
#define OFF_DINV     6450000    // float[50000] rsqrt(deg+1)
#define OFF_E        6500000    // float[50000]
#define OFF_PMIN     6550000    // float[256]
#define OFF_PS0      6550256    // float[256]
#define OFF_PS1      6550512    // float[256]
#define OFF_WT       6550768    // ushort[16384] bf16 W^T = 8192 floats
#define OFF_GCUR     6558960    // int[256] coarse-bucket cursors
#define OFF_PART     6559216    // uint[196*4096] partitioned edges
#define OFF_EBIN     7362032    // ushort[50000*64] node bins (src ids)

typedef __attribute__((ext_vector_type(8))) short bf16x8;
typedef __attribute__((ext_vector_type(4))) float f32x4;

__device__ __forceinline__ unsigned short f2bf(float f) {  // RNE
    unsigned u = __float_as_uint(f);
    unsigned r = u + 0x7fffu + ((u >> 16) & 1u);
    return (unsigned short)(r >> 16);
}
__device__ __forceinline__ float bflo(unsigned u) { return __uint_as_float(u << 16); }
__device__ __forceinline__ float bfhi(unsigned u) { return __uint_as_float(u & 0xffff0000u); }

// init: zero bucket cursors + build bf16 W^T in global ws (32 KB, one-off)
__global__ __launch_bounds__(256) void k_init(const float* __restrict__ W,
                                              int* __restrict__ gcursor,
                                              unsigned short* __restrict__ wtg) {
    int gtid = blockIdx.x * 256 + threadIdx.x;
    if (gtid < NBUCK) gcursor[gtid] = 0;
    if (gtid < 4096) {
        int k = gtid >> 5, n4 = (gtid & 31) * 4;
        float4 v = *(const float4*)(W + k * 128 + n4);
        wtg[(n4 + 0) * 128 + k] = f2bf(v.x);
        wtg[(n4 + 1) * 128 + k] = f2bf(v.y);
        wtg[(n4 + 2) * 128 + k] = f2bf(v.z);
        wtg[(n4 + 3) * 128 + k] = f2bf(v.w);
    }
}

// Pass 1: partition edges into 196 coarse dst-range buckets.
__global__ __launch_bounds__(256) void k_part(const int* __restrict__ src,
                                              const int* __restrict__ dst,
                                              int* __restrict__ gcursor,
                                              unsigned* __restrict__ part) {
    __shared__ int hist[NBUCK];
    __shared__ int base[NBUCK];
    int tid = threadIdx.x;
    if (tid < NBUCK) hist[tid] = 0;
    __syncthreads();
    int e0 = blockIdx.x * EPB;
    unsigned val[8]; int bk[8]; int rk[8];
    #pragma unroll
    for (int j = 0; j < 8; j++) {
        int e = e0 + j * 256 + tid;
        if (e < N_EDGES) {
            int s = src[e], d = dst[e];
            int bc = d >> 8;
            if ((unsigned)bc >= NBUCK) bc = NBUCK - 1;   // defensive clamp
            bk[j] = bc;
            val[j] = ((unsigned)(d & 255) << 16) | ((unsigned)s & 0xffffu);
            rk[j] = atomicAdd(&hist[bc], 1);
        } else { bk[j] = -1; val[j] = 0u; rk[j] = 0; }
    }
    __syncthreads();
    if (tid < NBUCK) base[tid] = atomicAdd(&gcursor[tid], hist[tid]);
    __syncthreads();
    #pragma unroll
    for (int j = 0; j < 8; j++) {
        if (bk[j] >= 0) {
            int p = base[bk[j]] + rk[j];
            if ((unsigned)p < BUCKCAP) part[bk[j] * BUCKCAP + p] = val[j];
        }
    }
}

// Pass 2: per-bucket LDS binning, coalesced writeout; emits deg + dinv.
__global__ __launch_bounds__(256) void k_bin(const int* __restrict__ gcursor,
                                             const unsigned* __restrict__ part,
                                             unsigned short* __restrict__ ebin,
                                             int* __restrict__ deg,
                                             float* __restrict__ dinv) {
    __shared__ __align__(16) unsigned short bins[256][MAXD];
    __shared__ int cnt[256];
    int tid = threadIdx.x, bkt = blockIdx.x;
    cnt[tid] = 0;
    __syncthreads();
    int M = gcursor[bkt];
    if (M > BUCKCAP) M = BUCKCAP;
    if (M < 0) M = 0;
    for (int i = tid; i < M; i += 256) {
        unsigned v = part[bkt * BUCKCAP + i];
        int ln = (v >> 16) & 255;
        int pos = atomicAdd(&cnt[ln], 1);
        if (pos < MAXD) bins[ln][pos] = (unsigned short)(v & 0xffffu);
    }
    __syncthreads();
    int node = bkt * 256 + tid;
    if (node < N_NODES) {
        int dg = cnt[tid]; if (dg > MAXD) dg = MAXD;
        deg[node] = dg;
        dinv[node] = rsqrtf((float)(dg + 1));
    }
    int nvalid = N_NODES - bkt * 256; if (nvalid > 256) nvalid = 256;
    if (nvalid < 0) nvalid = 0;
    int lim = nvalid * MAXD / 8;  // uint4 count
    const uint4* bs = (const uint4*)&bins[0][0];
    uint4* gb = (uint4*)(ebin + (size_t)bkt * 256 * MAXD);
    for (int i = tid; i < lim; i += 256) gb[i] = bs[i];
}

// Pure bf16 MFMA GEMM. Stores bf16(h * dinv_row), node-major [50000][128].
__global__ __launch_bounds__(256) void k_gemm(const float* __restrict__ x,
                                              const unsigned short* __restrict__ wtg,
                                              const float* __restrict__ dinv,
                                              unsigned short* __restrict__ htmpb) {
    int tid = threadIdx.x;
    int wave = tid >> 6, lane = tid & 63, quad = lane >> 4, m16 = lane & 15;
    int r0 = blockIdx.x * 32 + (wave & 1) * 16;
    int ch = (wave >> 1) * 4;               // col-tile base (4 tiles of 16)
    int arow = r0 + m16;
    int rowc = arow < N_NODES ? arow : N_NODES - 1;
    f32x4 acc[4];
    #pragma unroll
    for (int c = 0; c < 4; c++) acc[c] = (f32x4){0.f, 0.f, 0.f, 0.f};
    #pragma unroll
    for (int kt = 0; kt < 4; kt++) {
        int koff = kt * 32 + quad * 8;
        float4 xa = *(const float4*)(x + rowc * 128 + koff);
        float4 xb = *(const float4*)(x + rowc * 128 + koff + 4);
        bf16x8 af;
        af[0] = (short)f2bf(xa.x); af[1] = (short)f2bf(xa.y);
        af[2] = (short)f2bf(xa.z); af[3] = (short)f2bf(xa.w);
        af[4] = (short)f2bf(xb.x); af[5] = (short)f2bf(xb.y);
        af[6] = (short)f2bf(xb.z); af[7] = (short)f2bf(xb.w);
        #pragma unroll
        for (int c = 0; c < 4; c++) {
            bf16x8 bfrag = *(const bf16x8*)(wtg + ((ch + c) * 16 + m16) * 128 + koff);
            acc[c] = __builtin_amdgcn_mfma_f32_16x16x32_bf16(af, bfrag, acc[c], 0, 0, 0);
        }
    }
    #pragma unroll
    for (int reg = 0; reg < 4; reg++) {
        int grow = r0 + quad * 4 + reg;
        if (grow < N_NODES) {
            float dv = dinv[grow];
            #pragma unroll
            for (int c = 0; c < 4; c++)
                htmpb[grow * 128 + (ch + c) * 16 + m16] = f2bf(acc[c][reg] * dv);
        }
    }
}

// Gather, 16 lanes/node, uint4 (16B/lane): one wave covers 4 edges per VMEM
// instruction. 2 accumulator chains, 4-edge unroll.
__global__ __launch_bounds__(256) void k_gather(const unsigned short* __restrict__ htmpb,
                                                const int* __restrict__ deg,
                                                const float* __restrict__ dinv,
                                                const float* __restrict__ b,
                                                const unsigned short* __restrict__ ebin,
                                                float* __restrict__ out,
                                                unsigned short* __restrict__ obf) {
    int node = blockIdx.x * 16 + (threadIdx.x >> 4);
    int lane = threadIdx.x & 15;
    int c8 = lane * 8;                       // 8 bf16 cols per lane
    int dg = deg[node]; if (dg > MAXD) dg = MAXD; if (dg < 0) dg = 0;
    float di = dinv[node];
    float4 bv0 = *(const float4*)(b + c8);
    float4 bv1 = *(const float4*)(b + c8 + 4);
    uint4 hv = *(const uint4*)(htmpb + node * 128 + c8);
    float a0 = bflo(hv.x), a1 = bfhi(hv.x), a2 = bflo(hv.y), a3 = bfhi(hv.y);
    float a4 = bflo(hv.z), a5 = bfhi(hv.z), a6 = bflo(hv.w), a7 = bfhi(hv.w);
    float c0 = 0.f, c1 = 0.f, c2c = 0.f, c3 = 0.f, c4 = 0.f, c5 = 0.f, c6 = 0.f, c7 = 0.f;
    const unsigned short* bin = ebin + node * MAXD;
    int k = 0;
    for (; k + 3 < dg; k += 4) {
        uint2 bw = *(const uint2*)(bin + k);
        int s0 = bw.x & 0xffff, s1 = bw.x >> 16;
        int s2 = bw.y & 0xffff, s3 = bw.y >> 16;
        uint4 u0 = *(const uint4*)(htmpb + s0 * 128 + c8);
        uint4 u1 = *(const uint4*)(htmpb + s1 * 128 + c8);
        uint4 u2 = *(const uint4*)(htmpb + s2 * 128 + c8);
        uint4 u3 = *(const uint4*)(htmpb + s3 * 128 + c8);
        a0 += bflo(u0.x); a1 += bfhi(u0.x); a2 += bflo(u0.y); a3 += bfhi(u0.y);
        a4 += bflo(u0.z); a5 += bfhi(u0.z); a6 += bflo(u0.w); a7 += bfhi(u0.w);
        c0 += bflo(u1.x); c1 += bfhi(u1.x); c2c += bflo(u1.y); c3 += bfhi(u1.y);
        c4 += bflo(u1.z); c5 += bfhi(u1.z); c6 += bflo(u1.w); c7 += bfhi(u1.w);
        a0 += bflo(u2.x); a1 += bfhi(u2.x); a2 += bflo(u2.y); a3 += bfhi(u2.y);
        a4 += bflo(u2.z); a5 += bfhi(u2.z); a6 += bflo(u2.w); a7 += bfhi(u2.w);
        c0 += bflo(u3.x); c1 += bfhi(u3.x); c2c += bflo(u3.y); c3 += bfhi(u3.y);
        c4 += bflo(u3.z); c5 += bfhi(u3.z); c6 += bflo(u3.w); c7 += bfhi(u3.w);
    }
    for (; k < dg; k++) {
        int s0 = bin[k];
        uint4 u0 = *(const uint4*)(htmpb + s0 * 128 + c8);
        a0 += bflo(u0.x); a1 += bfhi(u0.x); a2 += bflo(u0.y); a3 += bfhi(u0.y);
        a4 += bflo(u0.z); a5 += bfhi(u0.z); a6 += bflo(u0.w); a7 += bfhi(u0.w);
    }
    a0 += c0; a1 += c1; a2 += c2c; a3 += c3; a4 += c4; a5 += c5; a6 += c6; a7 += c7;
    a0 = bv0.x + di * a0; a1 = bv0.y + di * a1; a2 = bv0.z + di * a2; a3 = bv0.w + di * a3;
    a4 = bv1.x + di * a4; a5 = bv1.y + di * a5; a6 = bv1.z + di * a6; a7 = bv1.w + di * a7;
    *(float4*)(out + node * 128 + c8)     = make_float4(a0, a1, a2, a3);
    *(float4*)(out + node * 128 + c8 + 4) = make_float4(a4, a5, a6, a7);
    uint4 pk;
    pk.x = (unsigned)f2bf(a0) | ((unsigned)f2bf(a1) << 16);
    pk.y = (unsigned)f2bf(a2) | ((unsigned)f2bf(a3) << 16);
    pk.z = (unsigned)f2bf(a4) | ((unsigned)f2bf(a5) << 16);
    pk.w = (unsigned)f2bf(a6) | ((unsigned)f2bf(a7) << 16);
    *(uint4*)(obf + node * 128 + c8) = pk;
}

// Energy, 16 lanes/node, uint4: E[d] = sum_s ||o_s - o_d||^2.
__global__ __launch_bounds__(256) void k_energy(const unsigned short* __restrict__ obf,
                                                const int* __restrict__ deg,
                                                const unsigned short* __restrict__ ebin,
                                                float* __restrict__ E) {
    int node = blockIdx.x * 16 + (threadIdx.x >> 4);
    int lane = threadIdx.x & 15;
    int c8 = lane * 8;
    int dg = deg[node]; if (dg > MAXD) dg = MAXD; if (dg < 0) dg = 0;
    uint4 ud = *(const uint4*)(obf + node * 128 + c8);
    float o0 = bflo(ud.x), o1 = bfhi(ud.x), o2 = bflo(ud.y), o3 = bfhi(ud.y);
    float o4 = bflo(ud.z), o5 = bfhi(ud.z), o6 = bflo(ud.w), o7 = bfhi(ud.w);
    float acc = 0.f, acc2 = 0.f;
    const unsigned short* bin = ebin + node * MAXD;
    int k = 0;
    for (; k + 3 < dg; k += 4) {
        uint2 bw = *(const uint2*)(bin + k);
        int s0 = bw.x & 0xffff, s1 = bw.x >> 16;
        int s2 = bw.y & 0xffff, s3 = bw.y >> 16;
        uint4 a = *(const uint4*)(obf + s0 * 128 + c8);
        uint4 c = *(const uint4*)(obf + s1 * 128 + c8);
        uint4 g = *(const uint4*)(obf + s2 * 128 + c8);
        uint4 h = *(const uint4*)(obf + s3 * 128 + c8);
        float d0, d1, d2, d3, d4, d5, d6, d7;
        d0 = bflo(a.x) - o0; d1 = bfhi(a.x) - o1; d2 = bflo(a.y) - o2; d3 = bfhi(a.y) - o3;
        d4 = bflo(a.z) - o4; d5 = bfhi(a.z) - o5; d6 = bflo(a.w) - o6; d7 = bfhi(a.w) - o7;
        acc  += d0*d0 + d1*d1 + d2*d2 + d3*d3 + d4*d4 + d5*d5 + d6*d6 + d7*d7;
        d0 = bflo(c.x) - o0; d1 = bfhi(c.x) - o1; d2 = bflo(c.y) - o2; d3 = bfhi(c.y) - o3;
        d4 = bflo(c.z) - o4; d5 = bfhi(c.z) - o5; d6 = bflo(c.w) - o6; d7 = bfhi(c.w) - o7;
        acc2 += d0*d0 + d1*d1 + d2*d2 + d3*d3 + d4*d4 + d5*d5 + d6*d6 + d7*d7;
        d0 = bflo(g.x) - o0; d1 = bfhi(g.x) - o1; d2 = bflo(g.y) - o2; d3 = bfhi(g.y) - o3;
        d4 = bflo(g.z) - o4; d5 = bfhi(g.z) - o5; d6 = bflo(g.w) - o6; d7 = bfhi(g.w) - o7;
        acc  += d0*d0 + d1*d1 + d2*d2 + d3*d3 + d4*d4 + d5*d5 + d6*d6 + d7*d7;
        d0 = bflo(h.x) - o0; d1 = bfhi(h.x) - o1; d2 = bflo(h.y) - o2; d3 = bfhi(h.y) - o3;
        d4 = bflo(h.z) - o4; d5 = bfhi(h.z) - o5; d6 = bflo(h.w) - o6; d7 = bfhi(h.w) - o7;
        acc2 += d0*d0 + d1*d1 + d2*d2 + d3*d3 + d4*d4 + d5*d5 + d6*d6 + d7*d7;
    }
    for (; k < dg; k++) {
        int s0 = bin[k];
        uint4 a = *(const uint4*)(obf + s0 * 128 + c8);
        float d0 = bflo(a.x) - o0, d1 = bfhi(a.x) - o1, d2 = bflo(a.y) - o2, d3 = bfhi(a.y) - o3;
        float d4 = bflo(a.z) - o4, d5 = bfhi(a.z) - o5, d6 = bflo(a.w) - o6, d7 = bfhi(a.w) - o7;
        acc += d0*d0 + d1*d1 + d2*d2 + d3*d3 + d4*d4 + d5*d5 + d6*d6 + d7*d7;
    }
    acc += acc2;
    #pragma unroll
    for (int off = 8; off; off >>= 1) acc += __shfl_xor(acc, off);  // 16-lane group
    if (lane == 0) E[node] = acc;
}

// 196 blocks: per-block partial min + partial softmax sums (local-min-shifted).
__global__ __launch_bounds__(256) void k_esoft(const float* __restrict__ E,
                                               const float* __restrict__ temp,
                                               float* __restrict__ pmin,
                                               float* __restrict__ ps0,
                                               float* __restrict__ ps1) {
    __shared__ float fred[12];
    int tid = threadIdx.x;
    int i = blockIdx.x * 256 + tid;
    int lane = tid & 63, wid = tid >> 6;
    float e = (i < N_NODES) ? E[i] : 3.402823466e38f;
    float m = e;
    #pragma unroll
    for (int off = 32; off; off >>= 1) m = fminf(m, __shfl_xor(m, off));
    if (lane == 0) fred[wid] = m;
    __syncthreads();
    float bm = fminf(fminf(fred[0], fred[1]), fminf(fred[2], fred[3]));
    float T = temp[0];
    float s0 = 0.f, s1 = 0.f;
    if (i < N_NODES) {
        float dd = (bm - e) / T;
        float ed = __expf(dd);
        s0 = ed; s1 = ed * dd;
    }
    #pragma unroll
    for (int off = 32; off; off >>= 1) { s0 += __shfl_xor(s0, off); s1 += __shfl_xor(s1, off); }
    __syncthreads();
    if (lane == 0) { fred[4 + wid] = s0; fred[8 + wid] = s1; }
    __syncthreads();
    if (tid == 0) {
        pmin[blockIdx.x] = bm;
        ps0[blockIdx.x] = fred[4] + fred[5] + fred[6] + fred[7];
        ps1[blockIdx.x] = fred[8] + fred[9] + fred[10] + fred[11];
    }
}

// Gradient: merge 196 partials (redundant per block), then sparse scatter.
__global__ __launch_bounds__(256) void k_grad(const int* __restrict__ deg,
                                              const unsigned short* __restrict__ ebin,
                                              const float* __restrict__ E,
                                              const float* __restrict__ temp,
                                              const float* __restrict__ pmin,
                                              const float* __restrict__ ps0,
                                              const float* __restrict__ ps1,
                                              const float* __restrict__ weight,
                                              float* __restrict__ out) {
    __shared__ float fred[12];
    int tid = threadIdx.x;
    int lane = tid & 63, wid = tid >> 6;

    float pm = (tid < NSCANB) ? pmin[tid] : 3.402823466e38f;
    float m = pm;
    #pragma unroll
    for (int off = 32; off; off >>= 1) m = fminf(m, __shfl_xor(m, off));
    if (lane == 0) fred[wid] = m;
    __syncthreads();
    float gmin = fminf(fminf(fred[0], fred[1]), fminf(fred[2], fred[3]));
    float T = temp[0];
    float s0 = 0.f, s1 = 0.f;
    if (tid < NSCANB) {
        float dl = (gmin - pm) / T;        // <= 0
        float ex = __expf(dl);
        float b0 = ps0[tid], b1 = ps1[tid];
        s0 = ex * b0;
        s1 = ex * (b1 + dl * b0);
    }
    #pragma unroll
    for (int off = 32; off; off >>= 1) { s0 += __shfl_xor(s0, off); s1 += __shfl_xor(s1, off); }
    __syncthreads();
    if (lane == 0) { fred[4 + wid] = s0; fred[8 + wid] = s1; }
    __syncthreads();
    float S0 = fred[4] + fred[5] + fred[6] + fred[7];
    float S1 = fred[8] + fred[9] + fred[10] + fred[11];

    float wscale = 2.f * weight[0];
    int lane32 = tid & 31;
    int node = blockIdx.x * 8 + (tid >> 5);
    if (node >= N_NODES) return;
    float dd = (gmin - E[node]) / T;
    float qd = (__expf(dd) / S0) * (dd - S1 / S0) / T;
    if (qd == 0.f) return;
    float cc = wscale * qd;
    int dg = deg[node]; if (dg > MAXD) dg = MAXD; if (dg < 0) dg = 0;
    float4 od = *(const float4*)(out + node * 128 + lane32 * 4);
    float sx = 0.f, sy = 0.f, sz = 0.f, sw = 0.f;
    const unsigned short* bin = ebin + node * MAXD;
    for (int k = 0; k < dg; k++) {
        int s = bin[k];
        if (s >= N_NODES) s = N_NODES - 1;   // keeps scatter inside d_out
        float4 a = *(const float4*)(out + s * 128 + lane32 * 4);
        float vx = cc * (a.x - od.x), vy = cc * (a.y - od.y);
        float vz = cc * (a.z - od.z), vw = cc * (a.w - od.w);
        float* os = out + s * 128 + lane32 * 4;
        atomicAdd(os + 0, vx); atomicAdd(os + 1, vy);
        atomicAdd(os + 2, vz); atomicAdd(os + 3, vw);
        sx += vx; sy += vy; sz += vz; sw += vw;
    }
    float* odp = out + node * 128 + lane32 * 4;
    atomicAdd(odp + 0, -sx); atomicAdd(odp + 1, -sy);
    atomicAdd(odp + 2, -sz); atomicAdd(odp + 3, -sw);
}

extern "C" void kernel_launch(void* const* d_in, const int* in_sizes, int n_in,
                              void* d_out, int out_size, void* d_ws, size_t ws_size,
                              hipStream_t stream) {
    const float* x      = (const float*)d_in[0];
    const int*   ei     = (const int*)d_in[1];
    const float* weight = (const float*)d_in[2];
    const float* temp   = (const float*)d_in[3];
    const float* W      = (const float*)d_in[4];
    const float* b      = (const float*)d_in[5];
    float* out = (float*)d_out;
    float* ws  = (float*)d_ws;

    const int* src = ei;
    const int* dst = ei + N_EDGES;

    unsigned short* htmpb = (unsigned short*)(ws + OFF_HTMPB);
    unsigned short* obf   = (unsigned short*)(ws + OFF_OBF);
    int*   deg      = (int*)(ws + OFF_DEG);
    float* dinv     = ws + OFF_DINV;
    float* Earr     = ws + OFF_E;
    float* pminA    = ws + OFF_PMIN;
    float* ps0A     = ws + OFF_PS0;
    float* ps1A     = ws + OFF_PS1;
    unsigned short* wtg = (unsigned short*)(ws + OFF_WT);
    int*   gcursor  = (int*)(ws + OFF_GCUR);
    unsigned* part  = (unsigned*)(ws + OFF_PART);
    unsigned short* ebin = (unsigned short*)(ws + OFF_EBIN);

    k_init<<<16, 256, 0, stream>>>(W, gcursor, wtg);
    k_part<<<NPARTB, 256, 0, stream>>>(src, dst, gcursor, part);
    k_bin<<<NBUCK, 256, 0, stream>>>(gcursor, part, ebin, deg, dinv);
    k_gemm<<<1563, 256, 0, stream>>>(x, wtg, dinv, htmpb);
    k_gather<<<3125, 256, 0, stream>>>(htmpb, deg, dinv, b, ebin, out, obf);
    k_energy<<<3125, 256, 0, stream>>>(obf, deg, ebin, Earr);
    k_esoft<<<NSCANB, 256, 0, stream>>>(Earr, temp, pminA, ps0A, ps1A);
    k_grad<<<6250, 256, 0, stream>>>(deg, ebin, Earr, temp, pminA, ps0A, ps1A, weight, out);
}